// Round 7
// baseline (155.248 us; speedup 1.0000x reference)
//
#include <hip/hip_runtime.h>
#include <stdint.h>

// Problem constants
#define DIMC   256
#define NHEADS 8
#define HD     32
#define BATCH  4
#define SEQ    2048
#define MTOT   (BATCH * SEQ)        // 8192 tokens
#define QKVN   (MTOT * HD * NHEADS) // 2097152 elements per q/k/v tensor
#define SCALE  0.17677669529663687f // 1/sqrt(32)
#define LOG2E  1.4426950408889634f
#define SCL2E  (SCALE * LOG2E)

typedef short bf16x8 __attribute__((ext_vector_type(8)));
typedef float f32x4  __attribute__((ext_vector_type(4)));

#if defined(__has_builtin)
#if __has_builtin(__builtin_amdgcn_exp2f)
#define EXP2F __builtin_amdgcn_exp2f
#else
#define EXP2F exp2f
#endif
#else
#define EXP2F exp2f
#endif

static __device__ __forceinline__ unsigned short f2bf(float f) {
    unsigned int u = __float_as_uint(f);
    u += 0x7fffu + ((u >> 16) & 1u);   // RNE
    return (unsigned short)(u >> 16);
}

// packed fp32x2 -> bf16x2 (single v_cvt_pk_bf16_f32 when available)
static __device__ __forceinline__ unsigned int cvt2(float a, float b) {
#if defined(__has_builtin) && __has_builtin(__builtin_amdgcn_cvt_pk_bf16_f32)
    typedef __bf16 bf2 __attribute__((ext_vector_type(2)));
    bf2 v = __builtin_amdgcn_cvt_pk_bf16_f32(a, b);
    return __builtin_bit_cast(unsigned int, v);
#else
    return (unsigned int)f2bf(a) | ((unsigned int)f2bf(b) << 16);
#endif
}

// ---------------------------------------------------------------------------
// Prep: fp32->bf16 conversion of x, qkv_w, proj_w; build QA (one-hot q%7)
// and KA (bias rows * LOG2E) augmentation tables [2048][32] bf16.
// ---------------------------------------------------------------------------
#define NX8   262144
#define NWQ8  24576
#define NWP8  8192
#define NQA8  8192
#define NKA8  8192
#define NPREP (NX8 + NWQ8 + NWP8 + NQA8 + NKA8)   // 311296

__global__ __launch_bounds__(256) void prep_kernel(
    const float* __restrict__ x, const float* __restrict__ wq,
    const float* __restrict__ wp, const float* __restrict__ table,
    unsigned short* __restrict__ xbf, unsigned short* __restrict__ wqbf,
    unsigned short* __restrict__ wpbf,
    unsigned short* __restrict__ QA, unsigned short* __restrict__ KA)
{
    int g = blockIdx.x * 256 + threadIdx.x;
    const float* src = nullptr;
    unsigned short* dst = nullptr;
    if (g < NX8)                      { src = x  + (size_t)g * 8;            dst = xbf  + (size_t)g * 8; }
    else if (g < NX8 + NWQ8)          { int l = g - NX8;        src = wq + (size_t)l * 8; dst = wqbf + (size_t)l * 8; }
    else if (g < NX8 + NWQ8 + NWP8)   { int l = g - NX8 - NWQ8; src = wp + (size_t)l * 8; dst = wpbf + (size_t)l * 8; }
    if (src) {
        float4 a0 = *(const float4*)src;
        float4 a1 = *(const float4*)(src + 4);
        uint4 pk;
        pk.x = cvt2(a0.x, a0.y); pk.y = cvt2(a0.z, a0.w);
        pk.z = cvt2(a1.x, a1.y); pk.w = cvt2(a1.z, a1.w);
        *(uint4*)dst = pk;
        return;
    }
    int l = g - (NX8 + NWQ8 + NWP8);
    if (l < NQA8) {
        int row = l >> 2, i0 = (l & 3) << 3, r7 = row % 7;
        unsigned short v[8];
        #pragma unroll
        for (int i = 0; i < 8; i++) v[i] = (i0 + i == r7) ? (unsigned short)0x3F80 : (unsigned short)0;
        *(uint4*)(QA + (size_t)row * 32 + i0) = *(const uint4*)v;
    } else if (l < NQA8 + NKA8) {
        l -= NQA8;
        int row = l >> 2, i0 = (l & 3) << 3, r7 = row % 7;
        unsigned short v[8];
        #pragma unroll
        for (int i = 0; i < 8; i++) {
            int ii = i0 + i;
            v[i] = (ii < 7) ? f2bf(table[ii - r7 + 6] * LOG2E) : (unsigned short)0;
        }
        *(uint4*)(KA + (size_t)row * 32 + i0) = *(const uint4*)v;
    }
}

// ---------------------------------------------------------------------------
// MFMA GEMM, W-tile staged ONCE in LDS (padded stride 36 -> no bank
// conflicts), A-frags direct from global.  out = A(Mx256) @ W(Nx256)^T + bias.
// MODE 0: QKV scatter; q pre-scaled by SCALE*log2e; V stored transposed
//         [bh][hd][seq] via an in-LDS block transpose (coalesced stores).
// MODE 1: fp32 store.  Block 256 = 4 waves; tile 64x64; wave owns 16 rows.
// ---------------------------------------------------------------------------
template<int MODE>
__global__ __launch_bounds__(256) void gemm_mfma_kernel(
    const unsigned short* __restrict__ A,
    const unsigned short* __restrict__ W,
    const float* __restrict__ bias,
    unsigned short* __restrict__ qb,
    unsigned short* __restrict__ kb,
    unsigned short* __restrict__ vtb,
    float* __restrict__ outf)
{
    // FW: [chunk][row][36] ushort (stride 18 dw -> conflict-free b128 reads)
    // same region reused as [64][65] f32 for the V transpose (16.6 KB < 36.9)
    __shared__ unsigned char LSD[8 * 64 * 36 * 2];
    unsigned short (*FW)[64][36] = (unsigned short (*)[64][36])LSD;
    float (*TR)[65] = (float (*)[65])LSD;

    const int t    = threadIdx.x;
    const int wave = t >> 6;
    const int lane = t & 63;
    const int cg   = lane & 15;
    const int quad = lane >> 4;
    const int m0   = blockIdx.y * 64;
    const int n0   = blockIdx.x * 64;

    {   // stage the whole 64x256 W tile, once
        int r = t >> 2, c8 = (t & 3) << 3;
        #pragma unroll
        for (int chunk = 0; chunk < 8; chunk++)
            *(bf16x8*)&FW[chunk][r][c8] =
                *(const bf16x8*)(W + (size_t)(n0 + r) * 256 + chunk * 32 + c8);
    }
    __syncthreads();

    const unsigned short* Arow = A + (size_t)(m0 + wave * 16 + cg) * 256 + quad * 8;

    f32x4 acc[4];
    #pragma unroll
    for (int c = 0; c < 4; c++) acc[c] = (f32x4){0.f, 0.f, 0.f, 0.f};

    #pragma unroll
    for (int chunk = 0; chunk < 8; chunk++) {
        bf16x8 af = *(const bf16x8*)(Arow + chunk * 32);
        bf16x8 wf[4];
        #pragma unroll
        for (int c = 0; c < 4; c++)
            wf[c] = *(const bf16x8*)&FW[chunk][c * 16 + cg][quad * 8];
        #pragma unroll
        for (int c = 0; c < 4; c++)
            acc[c] = __builtin_amdgcn_mfma_f32_16x16x32_bf16(af, wf[c], acc[c], 0, 0, 0);
    }

    // epilogue: C/D layout col = cg, row = quad*4 + reg
    if (MODE == 0 && blockIdx.x >= 8) {
        // pure-V block: transpose through LDS for coalesced Vt stores
        __syncthreads();   // FW reads done before region reuse
        #pragma unroll
        for (int c = 0; c < 4; c++) {
            int l = c * 16 + cg;              // local n
            float bv = bias[n0 + l];
            #pragma unroll
            for (int rr = 0; rr < 4; rr++)
                TR[l][wave * 16 + quad * 4 + rr] = acc[c][rr] + bv;
        }
        __syncthreads();
        int l  = t >> 2;                      // local n 0..63
        int mm = (t & 3) << 4;                // m offset 0,16,32,48
        int n  = n0 + l;
        int h  = (n >> 5) & 7;
        int d  = n & 31;
        int b_ = m0 >> 11;
        int nn = (m0 & 2047) + mm;
        float4 v0 = *(const float4*)&TR[l][mm];
        float4 v1 = *(const float4*)&TR[l][mm + 4];
        float4 v2 = *(const float4*)&TR[l][mm + 8];
        float4 v3 = *(const float4*)&TR[l][mm + 12];
        uint4 pk0, pk1;
        pk0.x = cvt2(v0.x, v0.y); pk0.y = cvt2(v0.z, v0.w);
        pk0.z = cvt2(v1.x, v1.y); pk0.w = cvt2(v1.z, v1.w);
        pk1.x = cvt2(v2.x, v2.y); pk1.y = cvt2(v2.z, v2.w);
        pk1.z = cvt2(v3.x, v3.y); pk1.w = cvt2(v3.z, v3.w);
        unsigned short* dst = vtb + ((size_t)((b_ * NHEADS + h) * HD + d)) * SEQ + nn;
        *(uint4*)dst       = pk0;
        *(uint4*)(dst + 8) = pk1;
        return;
    }

    #pragma unroll
    for (int c = 0; c < 4; c++) {
        int n = n0 + c * 16 + cg;
        float bv = bias[n];
        #pragma unroll
        for (int rr = 0; rr < 4; rr++) {
            int m = m0 + wave * 16 + quad * 4 + rr;
            float val = acc[c][rr] + bv;
            if (MODE == 0) {
                int which = n >> 8;        // 0 q, 1 k  (v handled above)
                int h     = (n >> 5) & 7;
                int d     = n & 31;
                int b_    = m >> 11;
                int nn    = m & 2047;
                int bh    = b_ * NHEADS + h;
                if (which == 0)
                    qb[((size_t)bh * SEQ + nn) * HD + d] = f2bf(val * SCL2E);
                else
                    kb[((size_t)bh * SEQ + nn) * HD + d] = f2bf(val);
            } else {
                outf[(size_t)m * 256 + n] = val;
            }
        }
    }
}

// ---------------------------------------------------------------------------
// Key-split MFMA flash attention. Block = 64 queries; 4 waves process the
// same queries over disjoint 512-key ranges (fixed-max softmax -> partials
// sum). S bias folded via QA/KA augmentation; softmax denominator computed
// by a ones-column PV MFMA (l = P @ 1, no VALU adds / shuffles). Per-wave P
// LDS region reused as the fp32 partial-output buffer at the end.
// Q,K: [bh][seq][32] bf16 (q pre-scaled).  Vt: [bh][32][seq].  AO: bf16.
// ---------------------------------------------------------------------------
__global__ __launch_bounds__(256) void attn_mfma_kernel(
    const unsigned short* __restrict__ Q,
    const unsigned short* __restrict__ K,
    const unsigned short* __restrict__ Vt,
    const unsigned short* __restrict__ QA,
    const unsigned short* __restrict__ KA,
    unsigned short* __restrict__ AO)
{
    // per-wave region: P (64 q x 64 k bf16, stride 72) OR [64][33] f32 partials
    __shared__ unsigned short PL[4][64][72];   // 36 KB

    const int t    = threadIdx.x;
    const int wave = t >> 6;
    const int lane = t & 63;
    const int cg   = lane & 15;
    const int quad = lane >> 4;

    const int bid = blockIdx.x;
    const int qt  = bid & 31;        // 32 query tiles of 64
    const int bh  = bid >> 5;
    const int b   = bh >> 3;
    const int h   = bh & 7;
    const int q0  = qt * 64;

    const unsigned short* Kbase = K  + (size_t)bh * (SEQ * HD);
    const unsigned short* Vbase = Vt + (size_t)bh * (SEQ * HD);

    // Q B-frags for 4 query sub-tiles: B[k=quad*8+j][n=cg]
    bf16x8 qf[4], qfa[4];
    #pragma unroll
    for (int qi = 0; qi < 4; qi++) {
        qf[qi]  = *(const bf16x8*)(Q + (size_t)bh * (SEQ * HD) +
                                   (size_t)(q0 + qi * 16 + cg) * HD + quad * 8);
        qfa[qi] = *(const bf16x8*)(QA + (size_t)(q0 + qi * 16 + cg) * HD + quad * 8);
    }

    bf16x8 ones;
    #pragma unroll
    for (int i = 0; i < 8; i++) ones[i] = (short)0x3F80;   // bf16 1.0

    f32x4 o[4][2], ol[4];
    #pragma unroll
    for (int qi = 0; qi < 4; qi++) {
        o[qi][0] = (f32x4){0.f, 0.f, 0.f, 0.f};
        o[qi][1] = (f32x4){0.f, 0.f, 0.f, 0.f};
        ol[qi]   = (f32x4){0.f, 0.f, 0.f, 0.f};
    }

    const int kstart = wave * (SEQ / 4);   // this wave's 512 keys
    #pragma unroll 2
    for (int jj = 0; jj < SEQ / 4; jj += 64) {
        const int j0 = kstart + jj;

        bf16x8 kf[4], kfa[4];
        #pragma unroll
        for (int jt = 0; jt < 4; jt++) {
            kf[jt]  = *(const bf16x8*)(Kbase + (size_t)(j0 + jt * 16 + cg) * HD + quad * 8);
            kfa[jt] = *(const bf16x8*)(KA    + (size_t)(j0 + jt * 16 + cg) * HD + quad * 8);
        }
        bf16x8 vf[2][2];
        #pragma unroll
        for (int kt = 0; kt < 2; kt++)
            #pragma unroll
            for (int dt = 0; dt < 2; dt++)
                vf[kt][dt] = *(const bf16x8*)(Vbase + (size_t)(dt * 16 + cg) * SEQ +
                                              j0 + kt * 32 + quad * 8);

        // S^T in two query-halves (limits live s-registers to 8 f32x4)
        #pragma unroll
        for (int half = 0; half < 2; half++) {
            f32x4 s[2][4];
            #pragma unroll
            for (int qh = 0; qh < 2; qh++) {
                int qi = half * 2 + qh;
                #pragma unroll
                for (int jt = 0; jt < 4; jt++) {
                    s[qh][jt] = __builtin_amdgcn_mfma_f32_16x16x32_bf16(
                        kfa[jt], qfa[qi], (f32x4){0.f, 0.f, 0.f, 0.f}, 0, 0, 0);
                    s[qh][jt] = __builtin_amdgcn_mfma_f32_16x16x32_bf16(
                        kf[jt], qf[qi], s[qh][jt], 0, 0, 0);
                }
            }
            #pragma unroll
            for (int qh = 0; qh < 2; qh++) {
                int qi = half * 2 + qh;
                #pragma unroll
                for (int jt = 0; jt < 4; jt++) {
                    float p0 = EXP2F(s[qh][jt][0]);
                    float p1 = EXP2F(s[qh][jt][1]);
                    float p2 = EXP2F(s[qh][jt][2]);
                    float p3 = EXP2F(s[qh][jt][3]);
                    uint2 w;
                    w.x = cvt2(p0, p1);
                    w.y = cvt2(p2, p3);
                    *(uint2*)&PL[wave][qi * 16 + cg][jt * 16 + quad * 4] = w;
                }
            }
        }
        __builtin_amdgcn_s_waitcnt(0xC07F);   // lgkmcnt(0): wave-local LDS RAW

        #pragma unroll
        for (int qi = 0; qi < 4; qi++) {
            bf16x8 pa0 = *(const bf16x8*)&PL[wave][qi * 16 + cg][quad * 8];
            bf16x8 pa1 = *(const bf16x8*)&PL[wave][qi * 16 + cg][32 + quad * 8];
            o[qi][0] = __builtin_amdgcn_mfma_f32_16x16x32_bf16(pa0, vf[0][0], o[qi][0], 0, 0, 0);
            o[qi][0] = __builtin_amdgcn_mfma_f32_16x16x32_bf16(pa1, vf[1][0], o[qi][0], 0, 0, 0);
            o[qi][1] = __builtin_amdgcn_mfma_f32_16x16x32_bf16(pa0, vf[0][1], o[qi][1], 0, 0, 0);
            o[qi][1] = __builtin_amdgcn_mfma_f32_16x16x32_bf16(pa1, vf[1][1], o[qi][1], 0, 0, 0);
            ol[qi]   = __builtin_amdgcn_mfma_f32_16x16x32_bf16(pa0, ones, ol[qi], 0, 0, 0);
            ol[qi]   = __builtin_amdgcn_mfma_f32_16x16x32_bf16(pa1, ones, ol[qi], 0, 0, 0);
        }
    }

    __builtin_amdgcn_s_waitcnt(0xC07F);   // drain P reads before region reuse
    // write fp32 partials into this wave's region: [64 q][33] (col 32 = l)
    float* OPw = (float*)&PL[wave][0][0];
    #pragma unroll
    for (int qi = 0; qi < 4; qi++) {
        #pragma unroll
        for (int dt = 0; dt < 2; dt++)
            #pragma unroll
            for (int rr = 0; rr < 4; rr++)
                OPw[(qi * 16 + quad * 4 + rr) * 33 + dt * 16 + cg] = o[qi][dt][rr];
        if (cg == 0) {
            #pragma unroll
            for (int rr = 0; rr < 4; rr++)
                OPw[(qi * 16 + quad * 4 + rr) * 33 + 32] = ol[qi][rr];
        }
    }
    __syncthreads();

    // final reduce over the 4 waves: thread t -> query t>>2, dims (t&3)*8..+7
    {
        int q  = t >> 2;
        int d0 = (t & 3) << 3;
        float l = 0.f;
        float ov[8];
        #pragma unroll
        for (int i = 0; i < 8; i++) ov[i] = 0.f;
        #pragma unroll
        for (int w = 0; w < 4; w++) {
            const float* OPx = (const float*)&PL[w][0][0];
            l += OPx[q * 33 + 32];
            #pragma unroll
            for (int i = 0; i < 8; i++) ov[i] += OPx[q * 33 + d0 + i];
        }
        float inv = 1.f / l;
        unsigned short pk[8];
        #pragma unroll
        for (int i = 0; i < 8; i += 2) {
            unsigned int u = cvt2(ov[i] * inv, ov[i + 1] * inv);
            pk[i]     = (unsigned short)(u & 0xffffu);
            pk[i + 1] = (unsigned short)(u >> 16);
        }
        *(uint4*)(AO + ((size_t)(b * SEQ + q0 + q)) * DIMC + h * HD + d0) = *(const uint4*)pk;
    }
}

// ---------------------------------------------------------------------------
extern "C" void kernel_launch(void* const* d_in, const int* in_sizes, int n_in,
                              void* d_out, int out_size, void* d_ws, size_t ws_size,
                              hipStream_t stream) {
    const float* x      = (const float*)d_in[0]; // (4,2048,256)
    const float* qkv_w  = (const float*)d_in[1]; // (768,256)
    const float* qkv_b  = (const float*)d_in[2]; // (768)
    const float* proj_w = (const float*)d_in[3]; // (256,256)
    const float* proj_b = (const float*)d_in[4]; // (256)
    const float* table  = (const float*)d_in[5]; // (104)
    float* out = (float*)d_out;                  // (4,2048,256) fp32

    unsigned short* ws   = (unsigned short*)d_ws;
    unsigned short* qb   = ws;                         // [bh][seq][32] bf16 (pre-scaled)
    unsigned short* kb   = qb  + (size_t)QKVN;
    unsigned short* vtb  = kb  + (size_t)QKVN;         // [bh][32][seq]
    unsigned short* ao   = vtb + (size_t)QKVN;         // [B*seq][256]
    unsigned short* xbf  = ao  + (size_t)QKVN;         // bf16 x
    unsigned short* wqbf = xbf + (size_t)QKVN;         // bf16 qkv_w (196608)
    unsigned short* wpbf = wqbf + 196608;              // bf16 proj_w (65536)
    unsigned short* QAt  = wpbf + 65536;               // [2048][32]
    unsigned short* KAt  = QAt  + 65536;               // [2048][32]

    // 0) convert inputs to bf16; build augmentation tables
    prep_kernel<<<dim3((NPREP + 255) / 256), 256, 0, stream>>>(
        x, qkv_w, proj_w, table, xbf, wqbf, wpbf, QAt, KAt);

    // 1) QKV GEMM (W staged once, padded LDS; V via in-LDS transpose)
    gemm_mfma_kernel<0><<<dim3(768 / 64, MTOT / 64), 256, 0, stream>>>(
        xbf, wqbf, qkv_b, qb, kb, vtb, nullptr);

    // 2) key-split MFMA flash attention (bias folded into augmented QK)
    attn_mfma_kernel<<<dim3(BATCH * NHEADS * (SEQ / 64)), 256, 0, stream>>>(
        qb, kb, vtb, QAt, KAt, ao);

    // 3) output projection (bf16 in, fp32 out)
    gemm_mfma_kernel<1><<<dim3(256 / 64, MTOT / 64), 256, 0, stream>>>(
        ao, wpbf, proj_b, nullptr, nullptr, nullptr, out);
}

// Round 8
// 131.271 us; speedup vs baseline: 1.1826x; 1.1826x over previous
//
#include <hip/hip_runtime.h>
#include <stdint.h>

// Problem constants
#define DIMC   256
#define NHEADS 8
#define HD     32
#define BATCH  4
#define SEQ    2048
#define MTOT   (BATCH * SEQ)        // 8192 tokens
#define QKVN   (MTOT * HD * NHEADS) // 2097152 elements per q/k/v tensor
#define SCALE  0.17677669529663687f // 1/sqrt(32)
#define LOG2E  1.4426950408889634f
#define SCL2E  (SCALE * LOG2E)

typedef short bf16x8 __attribute__((ext_vector_type(8)));
typedef float f32x4  __attribute__((ext_vector_type(4)));

#if defined(__has_builtin)
#if __has_builtin(__builtin_amdgcn_exp2f)
#define EXP2F __builtin_amdgcn_exp2f
#else
#define EXP2F exp2f
#endif
#else
#define EXP2F exp2f
#endif

static __device__ __forceinline__ unsigned short f2bf(float f) {
    unsigned int u = __float_as_uint(f);
    u += 0x7fffu + ((u >> 16) & 1u);   // RNE
    return (unsigned short)(u >> 16);
}

// packed fp32x2 -> bf16x2 (single v_cvt_pk_bf16_f32 when available)
static __device__ __forceinline__ unsigned int cvt2(float a, float b) {
#if defined(__has_builtin) && __has_builtin(__builtin_amdgcn_cvt_pk_bf16_f32)
    typedef __bf16 bf2 __attribute__((ext_vector_type(2)));
    bf2 v = __builtin_amdgcn_cvt_pk_bf16_f32(a, b);
    return __builtin_bit_cast(unsigned int, v);
#else
    return (unsigned int)f2bf(a) | ((unsigned int)f2bf(b) << 16);
#endif
}

// ---------------------------------------------------------------------------
// Prep: fp32->bf16 conversion of x, qkv_w, proj_w; build QA (one-hot q%7)
// and KA (bias rows * LOG2E) augmentation tables [2048][32] bf16.
// ---------------------------------------------------------------------------
#define NX8   262144
#define NWQ8  24576
#define NWP8  8192
#define NQA8  8192
#define NKA8  8192
#define NPREP (NX8 + NWQ8 + NWP8 + NQA8 + NKA8)   // 311296

__global__ __launch_bounds__(256) void prep_kernel(
    const float* __restrict__ x, const float* __restrict__ wq,
    const float* __restrict__ wp, const float* __restrict__ table,
    unsigned short* __restrict__ xbf, unsigned short* __restrict__ wqbf,
    unsigned short* __restrict__ wpbf,
    unsigned short* __restrict__ QA, unsigned short* __restrict__ KA)
{
    int g = blockIdx.x * 256 + threadIdx.x;
    const float* src = nullptr;
    unsigned short* dst = nullptr;
    if (g < NX8)                      { src = x  + (size_t)g * 8;            dst = xbf  + (size_t)g * 8; }
    else if (g < NX8 + NWQ8)          { int l = g - NX8;        src = wq + (size_t)l * 8; dst = wqbf + (size_t)l * 8; }
    else if (g < NX8 + NWQ8 + NWP8)   { int l = g - NX8 - NWQ8; src = wp + (size_t)l * 8; dst = wpbf + (size_t)l * 8; }
    if (src) {
        float4 a0 = *(const float4*)src;
        float4 a1 = *(const float4*)(src + 4);
        uint4 pk;
        pk.x = cvt2(a0.x, a0.y); pk.y = cvt2(a0.z, a0.w);
        pk.z = cvt2(a1.x, a1.y); pk.w = cvt2(a1.z, a1.w);
        *(uint4*)dst = pk;
        return;
    }
    int l = g - (NX8 + NWQ8 + NWP8);
    if (l < NQA8) {
        int row = l >> 2, i0 = (l & 3) << 3, r7 = row % 7;
        unsigned short v[8];
        #pragma unroll
        for (int i = 0; i < 8; i++) v[i] = (i0 + i == r7) ? (unsigned short)0x3F80 : (unsigned short)0;
        *(uint4*)(QA + (size_t)row * 32 + i0) = *(const uint4*)v;
    } else if (l < NQA8 + NKA8) {
        l -= NQA8;
        int row = l >> 2, i0 = (l & 3) << 3, r7 = row % 7;
        unsigned short v[8];
        #pragma unroll
        for (int i = 0; i < 8; i++) {
            int ii = i0 + i;
            v[i] = (ii < 7) ? f2bf(table[ii - r7 + 6] * LOG2E) : (unsigned short)0;
        }
        *(uint4*)(KA + (size_t)row * 32 + i0) = *(const uint4*)v;
    }
}

// ---------------------------------------------------------------------------
// MFMA GEMM. W-tile staged once in LDS with natural 16B alignment (b128 ops)
// and an XOR block swizzle: logical 8-ushort block cb of row r lives at
// physical block cb ^ ((r>>1)&3)  -> staging writes uniform, frag reads
// 2-way max (free).  A-frags direct from global (bf16, L2-hot).
// MODE 0: QKV scatter; q pre-scaled by SCALE*log2e; V stored transposed
//         [bh][hd][seq] via an in-LDS transpose reusing FW's memory as
//         float[64][68] (272B rows -> b128-able).
// MODE 1: fp32 store.  Block 256 = 4 waves; tile 64x64; wave owns 16 rows.
// ---------------------------------------------------------------------------
template<int MODE>
__global__ __launch_bounds__(256) void gemm_mfma_kernel(
    const unsigned short* __restrict__ A,
    const unsigned short* __restrict__ W,
    const float* __restrict__ bias,
    unsigned short* __restrict__ qb,
    unsigned short* __restrict__ kb,
    unsigned short* __restrict__ vtb,
    float* __restrict__ outf)
{
    __shared__ __align__(16) unsigned short FW[8][64][32];   // 32 KB

    const int t    = threadIdx.x;
    const int wave = t >> 6;
    const int lane = t & 63;
    const int cg   = lane & 15;
    const int quad = lane >> 4;
    const int m0   = blockIdx.y * 64;
    const int n0   = blockIdx.x * 64;

    {   // stage the whole 64x256 W tile once (swizzled)
        int r  = t >> 2, cb = t & 3;
        int pc = (cb ^ ((r >> 1) & 3)) << 3;
        #pragma unroll
        for (int chunk = 0; chunk < 8; chunk++)
            *(bf16x8*)&FW[chunk][r][pc] =
                *(const bf16x8*)(W + (size_t)(n0 + r) * 256 + chunk * 32 + cb * 8);
    }
    __syncthreads();

    const unsigned short* Arow = A + (size_t)(m0 + wave * 16 + cg) * 256 + quad * 8;
    const int rsw = ((cg >> 1) & 3);   // read swizzle term: rows c*16+cg -> (row>>1)&3

    f32x4 acc[4];
    #pragma unroll
    for (int c = 0; c < 4; c++) acc[c] = (f32x4){0.f, 0.f, 0.f, 0.f};

    #pragma unroll
    for (int chunk = 0; chunk < 8; chunk++) {
        bf16x8 af = *(const bf16x8*)(Arow + chunk * 32);
        bf16x8 wf[4];
        #pragma unroll
        for (int c = 0; c < 4; c++)
            wf[c] = *(const bf16x8*)&FW[chunk][c * 16 + cg][(quad ^ rsw) << 3];
        #pragma unroll
        for (int c = 0; c < 4; c++)
            acc[c] = __builtin_amdgcn_mfma_f32_16x16x32_bf16(af, wf[c], acc[c], 0, 0, 0);
    }

    // epilogue: C/D layout col = cg, row = quad*4 + reg
    if (MODE == 0 && blockIdx.x >= 8) {
        // pure-V block: transpose through LDS (reuse FW memory as f32[64][68])
        __syncthreads();   // all FW reads done before reuse
        float (*TR)[68] = (float (*)[68])(void*)&FW[0][0][0];
        #pragma unroll
        for (int c = 0; c < 4; c++) {
            int l = c * 16 + cg;              // local n
            float bv = bias[n0 + l];
            float4 vv;
            vv.x = acc[c][0] + bv; vv.y = acc[c][1] + bv;
            vv.z = acc[c][2] + bv; vv.w = acc[c][3] + bv;
            *(float4*)__builtin_assume_aligned(&TR[l][wave * 16 + quad * 4], 16) = vv;
        }
        __syncthreads();
        int l  = t >> 2;                      // local n 0..63
        int mm = (t & 3) << 4;                // m offset 0,16,32,48
        int n  = n0 + l;
        int h  = (n >> 5) & 7;
        int d  = n & 31;
        int b_ = m0 >> 11;
        int nn = (m0 & 2047) + mm;
        const float* tr = (const float*)__builtin_assume_aligned(&TR[l][mm], 16);
        float4 v0 = *(const float4*)(tr);
        float4 v1 = *(const float4*)(tr + 4);
        float4 v2 = *(const float4*)(tr + 8);
        float4 v3 = *(const float4*)(tr + 12);
        uint4 pk0, pk1;
        pk0.x = cvt2(v0.x, v0.y); pk0.y = cvt2(v0.z, v0.w);
        pk0.z = cvt2(v1.x, v1.y); pk0.w = cvt2(v1.z, v1.w);
        pk1.x = cvt2(v2.x, v2.y); pk1.y = cvt2(v2.z, v2.w);
        pk1.z = cvt2(v3.x, v3.y); pk1.w = cvt2(v3.z, v3.w);
        unsigned short* dst = vtb + ((size_t)((b_ * NHEADS + h) * HD + d)) * SEQ + nn;
        *(uint4*)dst       = pk0;
        *(uint4*)(dst + 8) = pk1;
        return;
    }

    #pragma unroll
    for (int c = 0; c < 4; c++) {
        int n = n0 + c * 16 + cg;
        float bv = bias[n];
        #pragma unroll
        for (int rr = 0; rr < 4; rr++) {
            int m = m0 + wave * 16 + quad * 4 + rr;
            float val = acc[c][rr] + bv;
            if (MODE == 0) {
                int which = n >> 8;        // 0 q, 1 k  (v handled above)
                int h     = (n >> 5) & 7;
                int d     = n & 31;
                int b_    = m >> 11;
                int nn    = m & 2047;
                int bh    = b_ * NHEADS + h;
                if (which == 0)
                    qb[((size_t)bh * SEQ + nn) * HD + d] = f2bf(val * SCL2E);
                else
                    kb[((size_t)bh * SEQ + nn) * HD + d] = f2bf(val);
            } else {
                outf[(size_t)m * 256 + n] = val;
            }
        }
    }
}

// ---------------------------------------------------------------------------
// Key-split MFMA flash attention. Block = 64 queries; 4 waves process the
// same queries over disjoint 512-key ranges (fixed-max softmax -> partials
// sum). S bias folded via QA/KA augmentation; softmax denominator via a
// ones-column PV MFMA (l = P @ 1). Per-wave P LDS region reused as the fp32
// partial-output buffer at the end.
// Q,K: [bh][seq][32] bf16 (q pre-scaled).  Vt: [bh][32][seq].  AO: bf16.
// ---------------------------------------------------------------------------
__global__ __launch_bounds__(256) void attn_mfma_kernel(
    const unsigned short* __restrict__ Q,
    const unsigned short* __restrict__ K,
    const unsigned short* __restrict__ Vt,
    const unsigned short* __restrict__ QA,
    const unsigned short* __restrict__ KA,
    unsigned short* __restrict__ AO)
{
    // per-wave region: P (64 q x 64 k bf16, stride 72) OR [64][33] f32 partials
    __shared__ __align__(16) unsigned short PL[4][64][72];   // 36 KB

    const int t    = threadIdx.x;
    const int wave = t >> 6;
    const int lane = t & 63;
    const int cg   = lane & 15;
    const int quad = lane >> 4;

    const int bid = blockIdx.x;
    const int qt  = bid & 31;        // 32 query tiles of 64
    const int bh  = bid >> 5;
    const int b   = bh >> 3;
    const int h   = bh & 7;
    const int q0  = qt * 64;

    const unsigned short* Kbase = K  + (size_t)bh * (SEQ * HD);
    const unsigned short* Vbase = Vt + (size_t)bh * (SEQ * HD);

    // Q B-frags for 4 query sub-tiles: B[k=quad*8+j][n=cg]
    bf16x8 qf[4], qfa[4];
    #pragma unroll
    for (int qi = 0; qi < 4; qi++) {
        qf[qi]  = *(const bf16x8*)(Q + (size_t)bh * (SEQ * HD) +
                                   (size_t)(q0 + qi * 16 + cg) * HD + quad * 8);
        qfa[qi] = *(const bf16x8*)(QA + (size_t)(q0 + qi * 16 + cg) * HD + quad * 8);
    }

    bf16x8 ones;
    #pragma unroll
    for (int i = 0; i < 8; i++) ones[i] = (short)0x3F80;   // bf16 1.0

    f32x4 o[4][2], ol[4];
    #pragma unroll
    for (int qi = 0; qi < 4; qi++) {
        o[qi][0] = (f32x4){0.f, 0.f, 0.f, 0.f};
        o[qi][1] = (f32x4){0.f, 0.f, 0.f, 0.f};
        ol[qi]   = (f32x4){0.f, 0.f, 0.f, 0.f};
    }

    const int kstart = wave * (SEQ / 4);   // this wave's 512 keys
    #pragma unroll 2
    for (int jj = 0; jj < SEQ / 4; jj += 64) {
        const int j0 = kstart + jj;

        bf16x8 kf[4], kfa[4];
        #pragma unroll
        for (int jt = 0; jt < 4; jt++) {
            kf[jt]  = *(const bf16x8*)(Kbase + (size_t)(j0 + jt * 16 + cg) * HD + quad * 8);
            kfa[jt] = *(const bf16x8*)(KA    + (size_t)(j0 + jt * 16 + cg) * HD + quad * 8);
        }
        bf16x8 vf[2][2];
        #pragma unroll
        for (int kt = 0; kt < 2; kt++)
            #pragma unroll
            for (int dt = 0; dt < 2; dt++)
                vf[kt][dt] = *(const bf16x8*)(Vbase + (size_t)(dt * 16 + cg) * SEQ +
                                              j0 + kt * 32 + quad * 8);

        // S^T in two query-halves (limits live s-registers to 8 f32x4)
        #pragma unroll
        for (int half = 0; half < 2; half++) {
            f32x4 s[2][4];
            #pragma unroll
            for (int qh = 0; qh < 2; qh++) {
                int qi = half * 2 + qh;
                #pragma unroll
                for (int jt = 0; jt < 4; jt++) {
                    s[qh][jt] = __builtin_amdgcn_mfma_f32_16x16x32_bf16(
                        kfa[jt], qfa[qi], (f32x4){0.f, 0.f, 0.f, 0.f}, 0, 0, 0);
                    s[qh][jt] = __builtin_amdgcn_mfma_f32_16x16x32_bf16(
                        kf[jt], qf[qi], s[qh][jt], 0, 0, 0);
                }
            }
            #pragma unroll
            for (int qh = 0; qh < 2; qh++) {
                int qi = half * 2 + qh;
                #pragma unroll
                for (int jt = 0; jt < 4; jt++) {
                    float p0 = EXP2F(s[qh][jt][0]);
                    float p1 = EXP2F(s[qh][jt][1]);
                    float p2 = EXP2F(s[qh][jt][2]);
                    float p3 = EXP2F(s[qh][jt][3]);
                    uint2 w;
                    w.x = cvt2(p0, p1);
                    w.y = cvt2(p2, p3);
                    *(uint2*)&PL[wave][qi * 16 + cg][jt * 16 + quad * 4] = w;
                }
            }
        }
        __builtin_amdgcn_s_waitcnt(0xC07F);   // lgkmcnt(0): wave-local LDS RAW

        #pragma unroll
        for (int qi = 0; qi < 4; qi++) {
            bf16x8 pa0 = *(const bf16x8*)&PL[wave][qi * 16 + cg][quad * 8];
            bf16x8 pa1 = *(const bf16x8*)&PL[wave][qi * 16 + cg][32 + quad * 8];
            o[qi][0] = __builtin_amdgcn_mfma_f32_16x16x32_bf16(pa0, vf[0][0], o[qi][0], 0, 0, 0);
            o[qi][0] = __builtin_amdgcn_mfma_f32_16x16x32_bf16(pa1, vf[1][0], o[qi][0], 0, 0, 0);
            o[qi][1] = __builtin_amdgcn_mfma_f32_16x16x32_bf16(pa0, vf[0][1], o[qi][1], 0, 0, 0);
            o[qi][1] = __builtin_amdgcn_mfma_f32_16x16x32_bf16(pa1, vf[1][1], o[qi][1], 0, 0, 0);
            ol[qi]   = __builtin_amdgcn_mfma_f32_16x16x32_bf16(pa0, ones, ol[qi], 0, 0, 0);
            ol[qi]   = __builtin_amdgcn_mfma_f32_16x16x32_bf16(pa1, ones, ol[qi], 0, 0, 0);
        }
    }

    __builtin_amdgcn_s_waitcnt(0xC07F);   // drain P reads before region reuse
    // write fp32 partials into this wave's region: [64 q][33] (col 32 = l)
    float* OPw = (float*)&PL[wave][0][0];
    #pragma unroll
    for (int qi = 0; qi < 4; qi++) {
        #pragma unroll
        for (int dt = 0; dt < 2; dt++)
            #pragma unroll
            for (int rr = 0; rr < 4; rr++)
                OPw[(qi * 16 + quad * 4 + rr) * 33 + dt * 16 + cg] = o[qi][dt][rr];
        if (cg == 0) {
            #pragma unroll
            for (int rr = 0; rr < 4; rr++)
                OPw[(qi * 16 + quad * 4 + rr) * 33 + 32] = ol[qi][rr];
        }
    }
    __syncthreads();

    // final reduce over the 4 waves: thread t -> query t>>2, dims (t&3)*8..+7
    {
        int q  = t >> 2;
        int d0 = (t & 3) << 3;
        float l = 0.f;
        float ov[8];
        #pragma unroll
        for (int i = 0; i < 8; i++) ov[i] = 0.f;
        #pragma unroll
        for (int w = 0; w < 4; w++) {
            const float* OPx = (const float*)&PL[w][0][0];
            l += OPx[q * 33 + 32];
            #pragma unroll
            for (int i = 0; i < 8; i++) ov[i] += OPx[q * 33 + d0 + i];
        }
        float inv = 1.f / l;
        unsigned short pk[8];
        #pragma unroll
        for (int i = 0; i < 8; i += 2) {
            unsigned int u = cvt2(ov[i] * inv, ov[i + 1] * inv);
            pk[i]     = (unsigned short)(u & 0xffffu);
            pk[i + 1] = (unsigned short)(u >> 16);
        }
        *(uint4*)(AO + ((size_t)(b * SEQ + q0 + q)) * DIMC + h * HD + d0) = *(const uint4*)pk;
    }
}

// ---------------------------------------------------------------------------
extern "C" void kernel_launch(void* const* d_in, const int* in_sizes, int n_in,
                              void* d_out, int out_size, void* d_ws, size_t ws_size,
                              hipStream_t stream) {
    const float* x      = (const float*)d_in[0]; // (4,2048,256)
    const float* qkv_w  = (const float*)d_in[1]; // (768,256)
    const float* qkv_b  = (const float*)d_in[2]; // (768)
    const float* proj_w = (const float*)d_in[3]; // (256,256)
    const float* proj_b = (const float*)d_in[4]; // (256)
    const float* table  = (const float*)d_in[5]; // (104)
    float* out = (float*)d_out;                  // (4,2048,256) fp32

    unsigned short* ws   = (unsigned short*)d_ws;
    unsigned short* qb   = ws;                         // [bh][seq][32] bf16 (pre-scaled)
    unsigned short* kb   = qb  + (size_t)QKVN;
    unsigned short* vtb  = kb  + (size_t)QKVN;         // [bh][32][seq]
    unsigned short* ao   = vtb + (size_t)QKVN;         // [B*seq][256]
    unsigned short* xbf  = ao  + (size_t)QKVN;         // bf16 x
    unsigned short* wqbf = xbf + (size_t)QKVN;         // bf16 qkv_w (196608)
    unsigned short* wpbf = wqbf + 196608;              // bf16 proj_w (65536)
    unsigned short* QAt  = wpbf + 65536;               // [2048][32]
    unsigned short* KAt  = QAt  + 65536;               // [2048][32]

    // 0) convert inputs to bf16; build augmentation tables
    prep_kernel<<<dim3((NPREP + 255) / 256), 256, 0, stream>>>(
        x, qkv_w, proj_w, table, xbf, wqbf, wpbf, QAt, KAt);

    // 1) QKV GEMM (aligned+swizzled W tile; V via in-LDS transpose)
    gemm_mfma_kernel<0><<<dim3(768 / 64, MTOT / 64), 256, 0, stream>>>(
        xbf, wqbf, qkv_b, qb, kb, vtb, nullptr);

    // 2) key-split MFMA flash attention (bias folded into augmented QK)
    attn_mfma_kernel<<<dim3(BATCH * NHEADS * (SEQ / 64)), 256, 0, stream>>>(
        qb, kb, vtb, QAt, KAt, ao);

    // 3) output projection (bf16 in, fp32 out)
    gemm_mfma_kernel<1><<<dim3(256 / 64, MTOT / 64), 256, 0, stream>>>(
        ao, wpbf, proj_b, nullptr, nullptr, nullptr, out);
}

// Round 10
// 130.446 us; speedup vs baseline: 1.1901x; 1.0063x over previous
//
#include <hip/hip_runtime.h>
#include <stdint.h>

// Problem constants
#define DIMC   256
#define NHEADS 8
#define HD     32
#define BATCH  4
#define SEQ    2048
#define MTOT   (BATCH * SEQ)        // 8192 tokens
#define QKVN   (MTOT * HD * NHEADS) // 2097152 elements per q/k/v tensor
#define SCALE  0.17677669529663687f // 1/sqrt(32)
#define LOG2E  1.4426950408889634f
#define SCL2E  (SCALE * LOG2E)

typedef short bf16x8 __attribute__((ext_vector_type(8)));
typedef float f32x4  __attribute__((ext_vector_type(4)));

#if defined(__has_builtin)
#if __has_builtin(__builtin_amdgcn_exp2f)
#define EXP2F __builtin_amdgcn_exp2f
#else
#define EXP2F exp2f
#endif
#else
#define EXP2F exp2f
#endif

static __device__ __forceinline__ unsigned short f2bf(float f) {
    unsigned int u = __float_as_uint(f);
    u += 0x7fffu + ((u >> 16) & 1u);   // RNE
    return (unsigned short)(u >> 16);
}

// packed fp32x2 -> bf16x2 (single v_cvt_pk_bf16_f32 when available)
static __device__ __forceinline__ unsigned int cvt2(float a, float b) {
#if defined(__has_builtin) && __has_builtin(__builtin_amdgcn_cvt_pk_bf16_f32)
    typedef __bf16 bf2 __attribute__((ext_vector_type(2)));
    bf2 v = __builtin_amdgcn_cvt_pk_bf16_f32(a, b);
    return __builtin_bit_cast(unsigned int, v);
#else
    return (unsigned int)f2bf(a) | ((unsigned int)f2bf(b) << 16);
#endif
}

// ---------------------------------------------------------------------------
// Prep: fp32->bf16 conversion of x, qkv_w, proj_w; build QA (one-hot q%7)
// and KA (bias rows * LOG2E) augmentation tables [2048][32] bf16.
// ---------------------------------------------------------------------------
#define NX8   262144
#define NWQ8  24576
#define NWP8  8192
#define NQA8  8192
#define NKA8  8192
#define NPREP (NX8 + NWQ8 + NWP8 + NQA8 + NKA8)   // 311296

__global__ __launch_bounds__(256) void prep_kernel(
    const float* __restrict__ x, const float* __restrict__ wq,
    const float* __restrict__ wp, const float* __restrict__ table,
    unsigned short* __restrict__ xbf, unsigned short* __restrict__ wqbf,
    unsigned short* __restrict__ wpbf,
    unsigned short* __restrict__ QA, unsigned short* __restrict__ KA)
{
    int g = blockIdx.x * 256 + threadIdx.x;
    const float* src = nullptr;
    unsigned short* dst = nullptr;
    if (g < NX8)                      { src = x  + (size_t)g * 8;            dst = xbf  + (size_t)g * 8; }
    else if (g < NX8 + NWQ8)          { int l = g - NX8;        src = wq + (size_t)l * 8; dst = wqbf + (size_t)l * 8; }
    else if (g < NX8 + NWQ8 + NWP8)   { int l = g - NX8 - NWQ8; src = wp + (size_t)l * 8; dst = wpbf + (size_t)l * 8; }
    if (src) {
        float4 a0 = *(const float4*)src;
        float4 a1 = *(const float4*)(src + 4);
        uint4 pk;
        pk.x = cvt2(a0.x, a0.y); pk.y = cvt2(a0.z, a0.w);
        pk.z = cvt2(a1.x, a1.y); pk.w = cvt2(a1.z, a1.w);
        *(uint4*)dst = pk;
        return;
    }
    int l = g - (NX8 + NWQ8 + NWP8);
    if (l < NQA8) {
        int row = l >> 2, i0 = (l & 3) << 3, r7 = row % 7;
        unsigned short v[8];
        #pragma unroll
        for (int i = 0; i < 8; i++) v[i] = (i0 + i == r7) ? (unsigned short)0x3F80 : (unsigned short)0;
        *(uint4*)(QA + (size_t)row * 32 + i0) = *(const uint4*)v;
    } else if (l < NQA8 + NKA8) {
        l -= NQA8;
        int row = l >> 2, i0 = (l & 3) << 3, r7 = row % 7;
        unsigned short v[8];
        #pragma unroll
        for (int i = 0; i < 8; i++) {
            int ii = i0 + i;
            v[i] = (ii < 7) ? f2bf(table[ii - r7 + 6] * LOG2E) : (unsigned short)0;
        }
        *(uint4*)(KA + (size_t)row * 32 + i0) = *(const uint4*)v;
    }
}

// ---------------------------------------------------------------------------
// QKV GEMM. 128x64 m,n tile per block (W-tile staged once, amortized over 2
// m-sub-tiles). W staged with 16B alignment + XOR block swizzle (2-way max).
// A-frags direct from global. q pre-scaled by SCALE*log2e; V stored
// transposed [bh][hd][seq] via an in-LDS transpose (reuses FW memory).
// ---------------------------------------------------------------------------
__global__ __launch_bounds__(256) void gemm_qkv_kernel(
    const unsigned short* __restrict__ A,
    const unsigned short* __restrict__ W,
    const float* __restrict__ bias,
    unsigned short* __restrict__ qb,
    unsigned short* __restrict__ kb,
    unsigned short* __restrict__ vtb)
{
    __shared__ __align__(16) unsigned short FW[8][64][32];   // 32 KB

    const int t    = threadIdx.x;
    const int wave = t >> 6;
    const int lane = t & 63;
    const int cg   = lane & 15;
    const int quad = lane >> 4;
    const int m0   = blockIdx.y * 128;
    const int n0   = blockIdx.x * 64;

    {   // stage the whole 64x256 W tile once (swizzled)
        int r  = t >> 2, cb = t & 3;
        int pc = (cb ^ ((r >> 1) & 3)) << 3;
        #pragma unroll
        for (int chunk = 0; chunk < 8; chunk++)
            *(bf16x8*)&FW[chunk][r][pc] =
                *(const bf16x8*)(W + (size_t)(n0 + r) * 256 + chunk * 32 + cb * 8);
    }
    __syncthreads();

    const unsigned short* Arow = A + (size_t)(m0 + wave * 16 + cg) * 256 + quad * 8;
    const int rsw = ((cg >> 1) & 3);   // read swizzle term

    f32x4 acc[2][4];
    #pragma unroll
    for (int s = 0; s < 2; s++)
        #pragma unroll
        for (int c = 0; c < 4; c++) acc[s][c] = (f32x4){0.f, 0.f, 0.f, 0.f};

    #pragma unroll
    for (int chunk = 0; chunk < 8; chunk++) {
        bf16x8 wf[4];
        #pragma unroll
        for (int c = 0; c < 4; c++)
            wf[c] = *(const bf16x8*)&FW[chunk][c * 16 + cg][(quad ^ rsw) << 3];
        #pragma unroll
        for (int s = 0; s < 2; s++) {
            bf16x8 af = *(const bf16x8*)(Arow + (size_t)s * 64 * 256 + chunk * 32);
            #pragma unroll
            for (int c = 0; c < 4; c++)
                acc[s][c] = __builtin_amdgcn_mfma_f32_16x16x32_bf16(af, wf[c], acc[s][c], 0, 0, 0);
        }
    }

    if (blockIdx.x >= 8) {
        // pure-V block: transpose through LDS (reuse FW memory as f32[64][68])
        float (*TR)[68] = (float (*)[68])(void*)&FW[0][0][0];
        #pragma unroll
        for (int s = 0; s < 2; s++) {
            __syncthreads();   // FW reads / previous TR pass done
            #pragma unroll
            for (int c = 0; c < 4; c++) {
                int l = c * 16 + cg;              // local n
                float bv = bias[n0 + l];
                float4 vv;
                vv.x = acc[s][c][0] + bv; vv.y = acc[s][c][1] + bv;
                vv.z = acc[s][c][2] + bv; vv.w = acc[s][c][3] + bv;
                *(float4*)__builtin_assume_aligned(&TR[l][wave * 16 + quad * 4], 16) = vv;
            }
            __syncthreads();
            int l  = t >> 2;                      // local n 0..63
            int mm = (t & 3) << 4;                // m offset 0,16,32,48
            int n  = n0 + l;
            int h  = (n >> 5) & 7;
            int d  = n & 31;
            int b_ = m0 >> 11;
            int nn = (m0 & 2047) + s * 64 + mm;
            const float* tr = (const float*)__builtin_assume_aligned(&TR[l][mm], 16);
            float4 v0 = *(const float4*)(tr);
            float4 v1 = *(const float4*)(tr + 4);
            float4 v2 = *(const float4*)(tr + 8);
            float4 v3 = *(const float4*)(tr + 12);
            uint4 pk0, pk1;
            pk0.x = cvt2(v0.x, v0.y); pk0.y = cvt2(v0.z, v0.w);
            pk0.z = cvt2(v1.x, v1.y); pk0.w = cvt2(v1.z, v1.w);
            pk1.x = cvt2(v2.x, v2.y); pk1.y = cvt2(v2.z, v2.w);
            pk1.z = cvt2(v3.x, v3.y); pk1.w = cvt2(v3.z, v3.w);
            unsigned short* dst = vtb + ((size_t)((b_ * NHEADS + h) * HD + d)) * SEQ + nn;
            *(uint4*)dst       = pk0;
            *(uint4*)(dst + 8) = pk1;
        }
        return;
    }

    #pragma unroll
    for (int s = 0; s < 2; s++) {
        #pragma unroll
        for (int c = 0; c < 4; c++) {
            int n = n0 + c * 16 + cg;
            float bv = bias[n];
            int which = n >> 8;        // 0 q, 1 k
            int h     = (n >> 5) & 7;
            int d     = n & 31;
            #pragma unroll
            for (int rr = 0; rr < 4; rr++) {
                int m = m0 + s * 64 + wave * 16 + quad * 4 + rr;
                float val = acc[s][c][rr] + bv;
                int b_ = m >> 11;
                int nn = m & 2047;
                int bh = b_ * NHEADS + h;
                if (which == 0)
                    qb[((size_t)bh * SEQ + nn) * HD + d] = f2bf(val * SCL2E);
                else
                    kb[((size_t)bh * SEQ + nn) * HD + d] = f2bf(val);
            }
        }
    }
}

// ---------------------------------------------------------------------------
// Projection GEMM. 64x64 tile; W staged once (swizzled); fp32 store.
// ---------------------------------------------------------------------------
__global__ __launch_bounds__(256) void gemm_proj_kernel(
    const unsigned short* __restrict__ A,
    const unsigned short* __restrict__ W,
    const float* __restrict__ bias,
    float* __restrict__ outf)
{
    __shared__ __align__(16) unsigned short FW[8][64][32];   // 32 KB

    const int t    = threadIdx.x;
    const int wave = t >> 6;
    const int lane = t & 63;
    const int cg   = lane & 15;
    const int quad = lane >> 4;
    const int m0   = blockIdx.y * 64;
    const int n0   = blockIdx.x * 64;

    {
        int r  = t >> 2, cb = t & 3;
        int pc = (cb ^ ((r >> 1) & 3)) << 3;
        #pragma unroll
        for (int chunk = 0; chunk < 8; chunk++)
            *(bf16x8*)&FW[chunk][r][pc] =
                *(const bf16x8*)(W + (size_t)(n0 + r) * 256 + chunk * 32 + cb * 8);
    }
    __syncthreads();

    const unsigned short* Arow = A + (size_t)(m0 + wave * 16 + cg) * 256 + quad * 8;
    const int rsw = ((cg >> 1) & 3);

    f32x4 acc[4];
    #pragma unroll
    for (int c = 0; c < 4; c++) acc[c] = (f32x4){0.f, 0.f, 0.f, 0.f};

    #pragma unroll
    for (int chunk = 0; chunk < 8; chunk++) {
        bf16x8 af = *(const bf16x8*)(Arow + chunk * 32);
        bf16x8 wf[4];
        #pragma unroll
        for (int c = 0; c < 4; c++)
            wf[c] = *(const bf16x8*)&FW[chunk][c * 16 + cg][(quad ^ rsw) << 3];
        #pragma unroll
        for (int c = 0; c < 4; c++)
            acc[c] = __builtin_amdgcn_mfma_f32_16x16x32_bf16(af, wf[c], acc[c], 0, 0, 0);
    }

    #pragma unroll
    for (int c = 0; c < 4; c++) {
        int n = n0 + c * 16 + cg;
        float bv = bias[n];
        #pragma unroll
        for (int rr = 0; rr < 4; rr++) {
            int m = m0 + wave * 16 + quad * 4 + rr;
            outf[(size_t)m * 256 + n] = acc[c][rr] + bv;
        }
    }
}

// ---------------------------------------------------------------------------
// Key-split MFMA flash attention (round-8 proven version). Block = 64
// queries; 4 waves over disjoint 512-key ranges (fixed-max softmax ->
// partials sum). Bias folded via QA/KA augmented MFMA; denominator via
// ones-column PV MFMA (l = P @ 1). P round-trips through a per-wave LDS
// region (C-layout -> A-layout); region reused for the final cross-wave
// fp32 partial-output exchange.
// Q,K: [bh][seq][32] bf16 (q pre-scaled).  Vt: [bh][32][seq].  AO: bf16.
// ---------------------------------------------------------------------------
__global__ __launch_bounds__(256) void attn_mfma_kernel(
    const unsigned short* __restrict__ Q,
    const unsigned short* __restrict__ K,
    const unsigned short* __restrict__ Vt,
    const unsigned short* __restrict__ QA,
    const unsigned short* __restrict__ KA,
    unsigned short* __restrict__ AO)
{
    // per-wave region: P (64 q x 64 k bf16, stride 72) OR [64][33] f32 partials
    __shared__ __align__(16) unsigned short PL[4][64][72];   // 36 KB

    const int t    = threadIdx.x;
    const int wave = t >> 6;
    const int lane = t & 63;
    const int cg   = lane & 15;
    const int quad = lane >> 4;

    const int bid = blockIdx.x;
    const int qt  = bid & 31;        // 32 query tiles of 64
    const int bh  = bid >> 5;
    const int b   = bh >> 3;
    const int h   = bh & 7;
    const int q0  = qt * 64;

    const unsigned short* Kbase = K  + (size_t)bh * (SEQ * HD);
    const unsigned short* Vbase = Vt + (size_t)bh * (SEQ * HD);

    // Q B-frags for 4 query sub-tiles: B[k=quad*8+j][n=cg]
    bf16x8 qf[4], qfa[4];
    #pragma unroll
    for (int qi = 0; qi < 4; qi++) {
        qf[qi]  = *(const bf16x8*)(Q + (size_t)bh * (SEQ * HD) +
                                   (size_t)(q0 + qi * 16 + cg) * HD + quad * 8);
        qfa[qi] = *(const bf16x8*)(QA + (size_t)(q0 + qi * 16 + cg) * HD + quad * 8);
    }

    bf16x8 ones;
    #pragma unroll
    for (int i = 0; i < 8; i++) ones[i] = (short)0x3F80;   // bf16 1.0

    f32x4 o[4][2], ol[4];
    #pragma unroll
    for (int qi = 0; qi < 4; qi++) {
        o[qi][0] = (f32x4){0.f, 0.f, 0.f, 0.f};
        o[qi][1] = (f32x4){0.f, 0.f, 0.f, 0.f};
        ol[qi]   = (f32x4){0.f, 0.f, 0.f, 0.f};
    }

    const int kstart = wave * (SEQ / 4);   // this wave's 512 keys
    #pragma unroll 2
    for (int jj = 0; jj < SEQ / 4; jj += 64) {
        const int j0 = kstart + jj;

        bf16x8 kf[4], kfa[4];
        #pragma unroll
        for (int jt = 0; jt < 4; jt++) {
            kf[jt]  = *(const bf16x8*)(Kbase + (size_t)(j0 + jt * 16 + cg) * HD + quad * 8);
            kfa[jt] = *(const bf16x8*)(KA    + (size_t)(j0 + jt * 16 + cg) * HD + quad * 8);
        }
        bf16x8 vf[2][2];
        #pragma unroll
        for (int kt = 0; kt < 2; kt++)
            #pragma unroll
            for (int dt = 0; dt < 2; dt++)
                vf[kt][dt] = *(const bf16x8*)(Vbase + (size_t)(dt * 16 + cg) * SEQ +
                                              j0 + kt * 32 + quad * 8);

        // S^T in two query-halves (limits live s-registers to 8 f32x4)
        #pragma unroll
        for (int half = 0; half < 2; half++) {
            f32x4 s[2][4];
            #pragma unroll
            for (int qh = 0; qh < 2; qh++) {
                int qi = half * 2 + qh;
                #pragma unroll
                for (int jt = 0; jt < 4; jt++) {
                    s[qh][jt] = __builtin_amdgcn_mfma_f32_16x16x32_bf16(
                        kfa[jt], qfa[qi], (f32x4){0.f, 0.f, 0.f, 0.f}, 0, 0, 0);
                    s[qh][jt] = __builtin_amdgcn_mfma_f32_16x16x32_bf16(
                        kf[jt], qf[qi], s[qh][jt], 0, 0, 0);
                }
            }
            #pragma unroll
            for (int qh = 0; qh < 2; qh++) {
                int qi = half * 2 + qh;
                #pragma unroll
                for (int jt = 0; jt < 4; jt++) {
                    float p0 = EXP2F(s[qh][jt][0]);
                    float p1 = EXP2F(s[qh][jt][1]);
                    float p2 = EXP2F(s[qh][jt][2]);
                    float p3 = EXP2F(s[qh][jt][3]);
                    uint2 w;
                    w.x = cvt2(p0, p1);
                    w.y = cvt2(p2, p3);
                    *(uint2*)&PL[wave][qi * 16 + cg][jt * 16 + quad * 4] = w;
                }
            }
        }
        __builtin_amdgcn_s_waitcnt(0xC07F);   // lgkmcnt(0): wave-local LDS RAW

        #pragma unroll
        for (int qi = 0; qi < 4; qi++) {
            bf16x8 pa0 = *(const bf16x8*)&PL[wave][qi * 16 + cg][quad * 8];
            bf16x8 pa1 = *(const bf16x8*)&PL[wave][qi * 16 + cg][32 + quad * 8];
            o[qi][0] = __builtin_amdgcn_mfma_f32_16x16x32_bf16(pa0, vf[0][0], o[qi][0], 0, 0, 0);
            o[qi][0] = __builtin_amdgcn_mfma_f32_16x16x32_bf16(pa1, vf[1][0], o[qi][0], 0, 0, 0);
            o[qi][1] = __builtin_amdgcn_mfma_f32_16x16x32_bf16(pa0, vf[0][1], o[qi][1], 0, 0, 0);
            o[qi][1] = __builtin_amdgcn_mfma_f32_16x16x32_bf16(pa1, vf[1][1], o[qi][1], 0, 0, 0);
            ol[qi]   = __builtin_amdgcn_mfma_f32_16x16x32_bf16(pa0, ones, ol[qi], 0, 0, 0);
            ol[qi]   = __builtin_amdgcn_mfma_f32_16x16x32_bf16(pa1, ones, ol[qi], 0, 0, 0);
        }
    }

    __builtin_amdgcn_s_waitcnt(0xC07F);   // drain P reads before region reuse
    // write fp32 partials into this wave's region: [64 q][33] (col 32 = l)
    float* OPw = (float*)&PL[wave][0][0];
    #pragma unroll
    for (int qi = 0; qi < 4; qi++) {
        #pragma unroll
        for (int dt = 0; dt < 2; dt++)
            #pragma unroll
            for (int rr = 0; rr < 4; rr++)
                OPw[(qi * 16 + quad * 4 + rr) * 33 + dt * 16 + cg] = o[qi][dt][rr];
        if (cg == 0) {
            #pragma unroll
            for (int rr = 0; rr < 4; rr++)
                OPw[(qi * 16 + quad * 4 + rr) * 33 + 32] = ol[qi][rr];
        }
    }
    __syncthreads();

    // final reduce over the 4 waves: thread t -> query t>>2, dims (t&3)*8..+7
    {
        int q  = t >> 2;
        int d0 = (t & 3) << 3;
        float l = 0.f;
        float ov[8];
        #pragma unroll
        for (int i = 0; i < 8; i++) ov[i] = 0.f;
        #pragma unroll
        for (int w = 0; w < 4; w++) {
            const float* OPx = (const float*)&PL[w][0][0];
            l += OPx[q * 33 + 32];
            #pragma unroll
            for (int i = 0; i < 8; i++) ov[i] += OPx[q * 33 + d0 + i];
        }
        float inv = 1.f / l;
        unsigned short pk[8];
        #pragma unroll
        for (int i = 0; i < 8; i += 2) {
            unsigned int u = cvt2(ov[i] * inv, ov[i + 1] * inv);
            pk[i]     = (unsigned short)(u & 0xffffu);
            pk[i + 1] = (unsigned short)(u >> 16);
        }
        *(uint4*)(AO + ((size_t)(b * SEQ + q0 + q)) * DIMC + h * HD + d0) = *(const uint4*)pk;
    }
}

// ---------------------------------------------------------------------------
extern "C" void kernel_launch(void* const* d_in, const int* in_sizes, int n_in,
                              void* d_out, int out_size, void* d_ws, size_t ws_size,
                              hipStream_t stream) {
    const float* x      = (const float*)d_in[0]; // (4,2048,256)
    const float* qkv_w  = (const float*)d_in[1]; // (768,256)
    const float* qkv_b  = (const float*)d_in[2]; // (768)
    const float* proj_w = (const float*)d_in[3]; // (256,256)
    const float* proj_b = (const float*)d_in[4]; // (256)
    const float* table  = (const float*)d_in[5]; // (104)
    float* out = (float*)d_out;                  // (4,2048,256) fp32

    unsigned short* ws   = (unsigned short*)d_ws;
    unsigned short* qb   = ws;                         // [bh][seq][32] bf16 (pre-scaled)
    unsigned short* kb   = qb  + (size_t)QKVN;
    unsigned short* vtb  = kb  + (size_t)QKVN;         // [bh][32][seq]
    unsigned short* ao   = vtb + (size_t)QKVN;         // [B*seq][256]
    unsigned short* xbf  = ao  + (size_t)QKVN;         // bf16 x
    unsigned short* wqbf = xbf + (size_t)QKVN;         // bf16 qkv_w (196608)
    unsigned short* wpbf = wqbf + 196608;              // bf16 proj_w (65536)
    unsigned short* QAt  = wpbf + 65536;               // [2048][32]
    unsigned short* KAt  = QAt  + 65536;               // [2048][32]

    // 0) convert inputs to bf16; build augmentation tables
    prep_kernel<<<dim3((NPREP + 255) / 256), 256, 0, stream>>>(
        x, qkv_w, proj_w, table, xbf, wqbf, wpbf, QAt, KAt);

    // 1) QKV GEMM (128x64 tiles; V via in-LDS transpose)
    gemm_qkv_kernel<<<dim3(768 / 64, MTOT / 128), 256, 0, stream>>>(
        xbf, wqbf, qkv_b, qb, kb, vtb);

    // 2) key-split MFMA flash attention (round-8 proven kernel)
    attn_mfma_kernel<<<dim3(BATCH * NHEADS * (SEQ / 64)), 256, 0, stream>>>(
        qb, kb, vtb, QAt, KAt, ao);

    // 3) output projection (bf16 in, fp32 out)
    gemm_proj_kernel<<<dim3(256 / 64, MTOT / 64), 256, 0, stream>>>(
        ao, wpbf, proj_b, out);
}